// Round 4
// baseline (204.796 us; speedup 1.0000x reference)
//
#include <hip/hip_runtime.h>
#include <cstdint>
#include <cstddef>

#define N_TOKENS 65536
#define DIM 64
#define K_CODES 1024
#define NTH 256
#define TPB 256                 // tokens per main block
#define NCH 16                  // chunks of 64 codes
#define NBLK (N_TOKENS / TPB)   // 256 main blocks

// out layout (floats): [0]=loss, [1..4194304]=quantized, [4194305]=perplexity,
// [4194306..4259841]=indices
#define OFF_Q 1
#define OFF_PERP 4194305
#define OFF_IDX 4194306

// fp16-split error <~1e-6; reference fp32 rounding jitter <~1.6e-5; margin 2.5e-5
#define MARGIN 2.5e-5f
// x scaled by 2^10, w by 2^16 (exact pow2) to keep fp16 splits normal
#define XSCALE 1024.0f
#define WSCALE 65536.0f
#define AINIT_SC -33554432.0f            // -0.5 * 2^26
#define D_UNSC  -2.9802322387695312e-08f // -2 * 2^-26 = -2^-25

// ws byte offsets
#define WS_LOSS   0        // double
#define WS_TICKET 8        // int
#define WS_COUNTS 16       // int[1024]
#define WS_WHI    4112     // _Float16[65536], 16B aligned, MFMA-swizzled, scaled 2^16
#define WS_WLO    135184   // _Float16[65536]
#define WS_S2     266256   // float[1024] exact np-order ||w||^2

typedef _Float16 f16x8 __attribute__((ext_vector_type(8)));
typedef float    f32x4 __attribute__((ext_vector_type(4)));

__device__ __forceinline__ float fmulr(float a, float b){ return __fmul_rn(a,b); }
__device__ __forceinline__ float faddr(float a, float b){ return __fadd_rn(a,b); }

__device__ __forceinline__ unsigned keyf(float f) {  // monotone float->u32
    unsigned u = __float_as_uint(f);
    return u ^ ((u & 0x80000000u) ? 0xffffffffu : 0x80000000u);
}

// split pre-scaled v into fp16 hi/lo (v - (float)h is exact: <=13 significant bits)
__device__ __forceinline__ void split16(float v, _Float16& h, _Float16& l) {
    h = (_Float16)v;
    l = (_Float16)(v - (float)h);
}

// numpy (AVX512 pairwise) sum of 64 squares — validated bit-exact rounds 1-3
__device__ float sumsq64_np(const float* __restrict__ p) {
    float s[16];
    #pragma unroll
    for (int l = 0; l < 16; ++l) {
        float a0 = fmulr(p[l],      p[l]);
        float a1 = fmulr(p[l + 16], p[l + 16]);
        float a2 = fmulr(p[l + 32], p[l + 32]);
        float a3 = fmulr(p[l + 48], p[l + 48]);
        s[l] = faddr(faddr(a0, a1), faddr(a2, a3));
    }
    #pragma unroll
    for (int len = 8; len >= 1; len >>= 1)
        #pragma unroll
        for (int l = 0; l < len; ++l)
            s[l] = faddr(s[l], s[l + len]);
    return s[0];
}

__device__ __forceinline__ void async_copy16(const void* g, void* l) {
    __builtin_amdgcn_global_load_lds(
        (const __attribute__((address_space(1))) void*)g,
        (__attribute__((address_space(3))) void*)l, 16, 0, 0);
}

// ---------------- prep: W -> swizzled fp16 hi/lo (scaled), exact s2, zero accs ---
__global__ void vq_prep(const float* __restrict__ W, _Float16* __restrict__ Whi,
                        _Float16* __restrict__ Wlo, float* __restrict__ s2g,
                        int* __restrict__ counts, int* __restrict__ ticket,
                        double* __restrict__ loss_acc) {
    int gid = blockIdx.x * NTH + threadIdx.x;   // 64 blocks -> 16384 threads
    for (int e = gid; e < K_CODES * DIM; e += 16384) {
        float vs = W[e] * WSCALE;               // exact pow2 scale
        _Float16 h, l; split16(vs, h, l);
        int j = e >> 6, k = e & 63;
        int pos = j * 64 + (((k >> 3) ^ (j & 7)) << 3) + (k & 7);
        Whi[pos] = h; Wlo[pos] = l;
    }
    if (gid < K_CODES) { s2g[gid] = sumsq64_np(W + gid * 64); counts[gid] = 0; }
    if (gid == 0) { *loss_acc = 0.0; *ticket = 0; }
}

// ---------------- main: MFMA approx + in-block exact fallback + merged finale ----
__global__ __launch_bounds__(NTH, 1)
void vq_main(const float* __restrict__ X, const float* __restrict__ W,
             const _Float16* __restrict__ WhiG, const _Float16* __restrict__ WloG,
             const float* __restrict__ s2g, float* __restrict__ out,
             double* __restrict__ loss_acc, int* __restrict__ counts,
             int* __restrict__ ticket) {
    __shared__ __align__(16) _Float16 xs_hi[TPB * 64];         // 32KB
    __shared__ __align__(16) _Float16 xs_lo[TPB * 64];         // 32KB
    __shared__ __align__(16) _Float16 ws_hi[2][64 * 64];       // dbuf 8KB each
    __shared__ __align__(16) _Float16 ws_lo[2][64 * 64];
    __shared__ __align__(16) float s2s[K_CODES];               // 4KB
    __shared__ int fidx[TPB];
    __shared__ int flist[TPB];
    __shared__ int fcount, lastFlag;
    __shared__ double lred[4];

    const int tid  = threadIdx.x;
    const int lane = tid & 63, wave = tid >> 6;
    const int quad = lane >> 4, lrow = lane & 15;
    const int t0   = blockIdx.x * TPB;

    if (tid == 0) fcount = 0;

    // prefetch chunk 0 (overlaps X staging)
    {
        const char* gh = (const char*)WhiG;
        const char* gl = (const char*)WloG;
        char* lh = (char*)&ws_hi[0][0] + wave * 1024;
        char* ll = (char*)&ws_lo[0][0] + wave * 1024;
        #pragma unroll
        for (int i = 0; i < 2; ++i) {
            async_copy16(gh + i * 4096 + tid * 16, lh + i * 4096);
            async_copy16(gl + i * 4096 + tid * 16, ll + i * 4096);
        }
    }
    // stage s2 (4KB)
    *(f32x4*)&s2s[tid * 4] = *(const f32x4*)&s2g[tid * 4];
    // stage X tile as swizzled fp16 hi/lo, scaled by 2^10 (2048 groups of 8 floats)
    #pragma unroll
    for (int i = 0; i < 8; ++i) {
        int g = tid + NTH * i;
        int t = g >> 3, kb = g & 7;
        const float* src = X + (size_t)(t0 + t) * DIM + kb * 8;
        float v[8];
        *(f32x4*)v       = *(const f32x4*)src;
        *(f32x4*)(v + 4) = *(const f32x4*)(src + 4);
        _Float16 h[8], l[8];
        #pragma unroll
        for (int k = 0; k < 8; ++k) split16(v[k] * XSCALE, h[k], l[k]);
        int base = t * 64 + ((kb ^ (t & 7)) << 3);
        *(f16x8*)&xs_hi[base] = *(f16x8*)h;
        *(f16x8*)&xs_lo[base] = *(f16x8*)l;
    }
    __syncthreads();   // X/s2 staged, chunk-0 prefetch drained

    // A fragments in registers: wave owns 64 tokens (4 row-tiles of 16)
    f16x8 a_h0[4], a_h1[4], a_l0[4], a_l1[4];
    #pragma unroll
    for (int rt = 0; rt < 4; ++rt) {
        int tf = wave * 64 + rt * 16 + lrow;
        int sA = tf & 7;
        a_h0[rt] = *(const f16x8*)&xs_hi[tf * 64 + (((0 + quad) ^ sA) << 3)];
        a_h1[rt] = *(const f16x8*)&xs_hi[tf * 64 + (((4 + quad) ^ sA) << 3)];
        a_l0[rt] = *(const f16x8*)&xs_lo[tf * 64 + (((0 + quad) ^ sA) << 3)];
        a_l1[rt] = *(const f16x8*)&xs_lo[tf * 64 + (((4 + quad) ^ sA) << 3)];
    }

    float r1v[16], r2v[16]; int r1i[16];
    #pragma unroll
    for (int ri = 0; ri < 16; ++ri) { r1v[ri] = 3.4e38f; r2v[ri] = 3.4e38f; r1i[ri] = 0x7fffffff; }

    for (int ch = 0; ch < NCH; ++ch) {
        const int buf = ch & 1;
        if (ch < NCH - 1) {   // prefetch next chunk; stays in flight all chunk
            const char* gh = (const char*)WhiG + (ch + 1) * 8192;
            const char* gl = (const char*)WloG + (ch + 1) * 8192;
            char* lh = (char*)&ws_hi[buf ^ 1][0] + wave * 1024;
            char* ll = (char*)&ws_lo[buf ^ 1][0] + wave * 1024;
            #pragma unroll
            for (int i = 0; i < 2; ++i) {
                async_copy16(gh + i * 4096 + tid * 16, lh + i * 4096);
                async_copy16(gl + i * 4096 + tid * 16, ll + i * 4096);
            }
        }
        #pragma unroll
        for (int ct = 0; ct < 4; ++ct) {
            int lc = ct * 16 + lrow;          // local code (this lane's C-column)
            int sB = lrow & 7;
            const _Float16* bh = &ws_hi[buf][lc * 64];
            const _Float16* bl = &ws_lo[buf][lc * 64];
            f16x8 b_h0 = *(const f16x8*)&bh[((0 + quad) ^ sB) << 3];
            f16x8 b_h1 = *(const f16x8*)&bh[((4 + quad) ^ sB) << 3];
            f16x8 b_l0 = *(const f16x8*)&bl[((0 + quad) ^ sB) << 3];
            f16x8 b_l1 = *(const f16x8*)&bl[((4 + quad) ^ sB) << 3];
            int jcode = ch * 64 + lc;
            float ainit = fmulr(s2s[jcode], AINIT_SC);   // -0.5*s2*2^26
            #pragma unroll
            for (int rt = 0; rt < 4; ++rt) {
                f32x4 acc = {ainit, ainit, ainit, ainit};
                acc = __builtin_amdgcn_mfma_f32_16x16x32_f16(a_h0[rt], b_h0, acc, 0, 0, 0);
                acc = __builtin_amdgcn_mfma_f32_16x16x32_f16(a_h1[rt], b_h1, acc, 0, 0, 0);
                acc = __builtin_amdgcn_mfma_f32_16x16x32_f16(a_h0[rt], b_l0, acc, 0, 0, 0);
                acc = __builtin_amdgcn_mfma_f32_16x16x32_f16(a_h1[rt], b_l1, acc, 0, 0, 0);
                acc = __builtin_amdgcn_mfma_f32_16x16x32_f16(a_l0[rt], b_h0, acc, 0, 0, 0);
                acc = __builtin_amdgcn_mfma_f32_16x16x32_f16(a_l1[rt], b_h1, acc, 0, 0, 0);
                #pragma unroll
                for (int r = 0; r < 4; ++r) {
                    float d = fmulr(acc[r], D_UNSC);    // -2*acc/2^26
                    int ri = rt * 4 + r;
                    bool lt = d < r1v[ri];              // strict: earliest code on ties
                    float sec = lt ? r1v[ri] : d;
                    r2v[ri] = fminf(r2v[ri], sec);
                    r1v[ri] = lt ? d : r1v[ri];
                    r1i[ri] = lt ? jcode : r1i[ri];
                }
            }
        }
        __syncthreads();   // drains next-chunk prefetch; protects buf reuse
    }

    // butterfly top-2 merge across the 16 lrow lanes (codes disjoint per lane)
    #pragma unroll
    for (int m = 1; m <= 8; m <<= 1) {
        #pragma unroll
        for (int ri = 0; ri < 16; ++ri) {
            float o1v = __shfl_xor(r1v[ri], m, 64);
            int   o1i = __shfl_xor(r1i[ri], m, 64);
            float o2v = __shfl_xor(r2v[ri], m, 64);
            bool take = (o1v < r1v[ri]) || (o1v == r1v[ri] && o1i < r1i[ri]);
            float loser = take ? r1v[ri] : o1v;
            r2v[ri] = fminf(fminf(r2v[ri], o2v), loser);
            if (take) { r1v[ri] = o1v; r1i[ri] = o1i; }
        }
    }
    if (lrow == 0) {
        #pragma unroll
        for (int ri = 0; ri < 16; ++ri) {
            int rt = ri >> 2, r = ri & 3;
            int t = wave * 64 + rt * 16 + quad * 4 + r;
            bool fb = (r2v[ri] - r1v[ri]) < MARGIN;
            fidx[t] = fb ? (r1i[ri] | (int)0x80000000) : r1i[ri];
            if (fb) { int p = atomicAdd(&fcount, 1); flist[p] = t; }
        }
    }
    __syncthreads();

    // epilogue for certain tokens, float4-vectorized
    double lsum = 0.0;
    #pragma unroll
    for (int i = 0; i < 16; ++i) {
        int e4 = tid + NTH * i;              // 0..4095 float4 groups
        int t = e4 >> 4, d4 = (e4 & 15) * 4;
        int iv = fidx[t];
        if (iv >= 0) {
            f32x4 q = *(const f32x4*)&W[iv * 64 + d4];
            f32x4 x = *(const f32x4*)&X[(size_t)(t0 + t) * 64 + d4];
            *(f32x4*)&out[(size_t)OFF_Q + (size_t)(t0 + t) * 64 + d4] = q;
            #pragma unroll
            for (int c = 0; c < 4; ++c) {
                float df = __fsub_rn(q[c], x[c]);
                lsum += (double)fmulr(df, df);
            }
        }
    }
    #pragma unroll
    for (int off = 32; off >= 1; off >>= 1) lsum += __shfl_down(lsum, off, 64);
    if (lane == 0) lred[wave] = lsum;
    if (tid < TPB) {
        int iv = fidx[tid];
        if (iv >= 0) {
            atomicAdd(&counts[iv], 1);
            out[(size_t)OFF_IDX + t0 + tid] = (float)iv;
        }
    }
    __syncthreads();
    if (tid == 0) atomicAdd(loss_acc, lred[0] + lred[1] + lred[2] + lred[3]);

    // ---- in-block exact fallback: one wave per marginal token, W from L2 --------
    // bit-exact round-1 arithmetic: sequential-k fp32 FMA chain, np tie-break
    for (int fi = wave; fi < fcount; fi += 4) {
        int t = flist[fi];
        int gtok = t0 + t;
        float s1v = sumsq64_np(X + (size_t)gtok * 64);   // broadcast loads
        f32x4 xr[16];
        #pragma unroll
        for (int kb = 0; kb < 16; ++kb)
            xr[kb] = *(const f32x4*)(X + (size_t)gtok * 64 + kb * 4);
        unsigned long long best = ~0ULL;
        #pragma unroll 1
        for (int c16 = 0; c16 < 16; ++c16) {
            int code = lane * 16 + c16;
            const float* wr = W + code * 64;
            float acc = 0.0f;
            #pragma unroll
            for (int kb = 0; kb < 16; ++kb) {
                f32x4 wv = *(const f32x4*)(wr + kb * 4);
                acc = __builtin_fmaf(xr[kb][0], wv[0], acc);
                acc = __builtin_fmaf(xr[kb][1], wv[1], acc);
                acc = __builtin_fmaf(xr[kb][2], wv[2], acc);
                acc = __builtin_fmaf(xr[kb][3], wv[3], acc);
            }
            float d = faddr(faddr(s1v, s2s[code]), fmulr(-2.0f, acc));
            unsigned long long pk = ((unsigned long long)keyf(d) << 32) | (unsigned)code;
            best = pk < best ? pk : best;
        }
        #pragma unroll
        for (int m = 32; m >= 1; m >>= 1) {
            unsigned long long o = __shfl_xor(best, m, 64);
            best = o < best ? o : best;
        }
        int idx = (int)(best & 0xffffffffu);
        float q = W[idx * 64 + lane];
        float x = X[(size_t)gtok * 64 + lane];
        out[(size_t)OFF_Q + (size_t)gtok * 64 + lane] = q;
        float df = __fsub_rn(q, x);
        double ls = (double)fmulr(df, df);
        #pragma unroll
        for (int m = 32; m >= 1; m >>= 1) ls += __shfl_xor(ls, m, 64);
        if (lane == 0) {
            out[(size_t)OFF_IDX + gtok] = (float)idx;
            atomicAdd(&counts[idx], 1);
            atomicAdd(loss_acc, ls);
        }
    }

    // ---- merged finale: last block to finish computes loss & perplexity ---------
    __syncthreads();               // all threads' global ops drained (vmcnt 0)
    if (tid == 0) {
        __threadfence();
        int old = atomicAdd(ticket, 1);
        lastFlag = (old == NBLK - 1) ? 1 : 0;
    }
    __syncthreads();
    if (lastFlag) {
        double h = 0.0;
        for (int j = tid; j < K_CODES; j += NTH) {
            int c = atomicAdd(&counts[j], 0);        // device-coherent read
            double p = (double)c / 65536.0;
            h += p * log(p + 1e-10);
        }
        #pragma unroll
        for (int off = 32; off >= 1; off >>= 1) h += __shfl_down(h, off, 64);
        if (lane == 0) lred[wave] = h;
        __syncthreads();
        if (tid == 0) {
            double H = lred[0] + lred[1] + lred[2] + lred[3];
            out[OFF_PERP] = (float)exp(-H);
            double ls = atomicAdd(loss_acc, 0.0);    // device-coherent read
            float Lf = (float)(ls / 4194304.0);
            out[0] = faddr(Lf, fmulr(0.25f, Lf));
        }
    }
}

extern "C" void kernel_launch(void* const* d_in, const int* in_sizes, int n_in,
                              void* d_out, int out_size, void* d_ws, size_t ws_size,
                              hipStream_t stream) {
    const float* X = (const float*)d_in[0];
    const float* W = (const float*)d_in[1];
    float* out = (float*)d_out;
    char* ws = (char*)d_ws;
    double* loss_acc = (double*)(ws + WS_LOSS);
    int* ticket = (int*)(ws + WS_TICKET);
    int* counts = (int*)(ws + WS_COUNTS);
    _Float16* Whi = (_Float16*)(ws + WS_WHI);
    _Float16* Wlo = (_Float16*)(ws + WS_WLO);
    float* s2g = (float*)(ws + WS_S2);

    vq_prep<<<64, NTH, 0, stream>>>(W, Whi, Wlo, s2g, counts, ticket, loss_acc);
    vq_main<<<NBLK, NTH, 0, stream>>>(X, W, Whi, Wlo, s2g, out,
                                      loss_acc, counts, ticket);
}

// Round 5
// 187.139 us; speedup vs baseline: 1.0944x; 1.0944x over previous
//
#include <hip/hip_runtime.h>
#include <cstdint>
#include <cstddef>

#define N_TOKENS 65536
#define DIM 64
#define K_CODES 1024
#define NTH 256
#define TPB 128                 // tokens per block (2 waves x 64 tokens)
#define NBLK (N_TOKENS / TPB)   // 512 blocks = 2 blocks/CU

// out layout (floats): [0]=loss, [1..4194304]=quantized, [4194305]=perplexity,
// [4194306..4259841]=indices
#define OFF_Q 1
#define OFF_PERP 4194305
#define OFF_IDX 4194306

// fp16-split error <~1.5e-6; reference fp32 rounding jitter <~1.6e-5; margin 2.5e-5
// (validated round 4: passed with absmax 3.8e-6)
#define MARGIN 2.5e-5f
// x scaled by 2^10, w by 2^16 (exact pow2) to keep fp16 splits normal
#define XSCALE 1024.0f
#define WSCALE 65536.0f
#define AINIT_SC -33554432.0f            // -0.5 * 2^26
#define D_UNSC  -2.9802322387695312e-08f // -2 * 2^-26 = -2^-25

// ws byte offsets
#define WS_LOSS   0        // double
#define WS_TICKET 8        // int
#define WS_COUNTS 16       // int[1024]
#define WS_WHI    4112     // _Float16[65536] row-major [code][k], scaled 2^16
#define WS_WLO    135184   // _Float16[65536]
#define WS_S2     266256   // float[1024] exact np-order ||w||^2

typedef _Float16 f16x8 __attribute__((ext_vector_type(8)));
typedef _Float16 f16x4 __attribute__((ext_vector_type(4)));
typedef float    f32x4 __attribute__((ext_vector_type(4)));

__device__ __forceinline__ float fmulr(float a, float b){ return __fmul_rn(a,b); }
__device__ __forceinline__ float faddr(float a, float b){ return __fadd_rn(a,b); }

__device__ __forceinline__ unsigned keyf(float f) {  // monotone float->u32
    unsigned u = __float_as_uint(f);
    return u ^ ((u & 0x80000000u) ? 0xffffffffu : 0x80000000u);
}

// split pre-scaled v into fp16 hi/lo (v - (float)h exact: residual <=13 sig bits)
__device__ __forceinline__ void split16(float v, _Float16& h, _Float16& l) {
    h = (_Float16)v;
    l = (_Float16)(v - (float)h);
}

// numpy (AVX512 pairwise) sum of 64 squares — validated bit-exact rounds 1-4
__device__ float sumsq64_np(const float* __restrict__ p) {
    float s[16];
    #pragma unroll
    for (int l = 0; l < 16; ++l) {
        float a0 = fmulr(p[l],      p[l]);
        float a1 = fmulr(p[l + 16], p[l + 16]);
        float a2 = fmulr(p[l + 32], p[l + 32]);
        float a3 = fmulr(p[l + 48], p[l + 48]);
        s[l] = faddr(faddr(a0, a1), faddr(a2, a3));
    }
    #pragma unroll
    for (int len = 8; len >= 1; len >>= 1)
        #pragma unroll
        for (int l = 0; l < len; ++l)
            s[l] = faddr(s[l], s[l + len]);
    return s[0];
}

// ---------------- prep: W -> row-major fp16 hi/lo (scaled), exact s2, zero accs --
__global__ void vq_prep(const float* __restrict__ W, _Float16* __restrict__ Whi,
                        _Float16* __restrict__ Wlo, float* __restrict__ s2g,
                        int* __restrict__ counts, int* __restrict__ ticket,
                        double* __restrict__ loss_acc) {
    int gid = blockIdx.x * NTH + threadIdx.x;   // 128 blocks -> 32768 threads
    if (gid < 16384) {                           // one float4 per thread
        f32x4 v = *(const f32x4*)(W + gid * 4);
        f16x4 h, l;
        #pragma unroll
        for (int j = 0; j < 4; ++j) {
            _Float16 hh, ll; split16(v[j] * WSCALE, hh, ll);
            h[j] = hh; l[j] = ll;
        }
        *(f16x4*)(Whi + gid * 4) = h;
        *(f16x4*)(Wlo + gid * 4) = l;
    }
    if (gid < K_CODES) { s2g[gid] = sumsq64_np(W + gid * 64); counts[gid] = 0; }
    if (gid == 0) { *loss_acc = 0.0; *ticket = 0; }
}

// ---------------- main: barrier-free MFMA scan + merge + fallback + finale -------
__global__ __launch_bounds__(NTH, 2)
void vq_main(const float* __restrict__ X, const float* __restrict__ W,
             const _Float16* __restrict__ WhiG, const _Float16* __restrict__ WloG,
             const float* __restrict__ s2g, float* __restrict__ out,
             double* __restrict__ loss_acc, int* __restrict__ counts,
             int* __restrict__ ticket) {
    __shared__ float m1v[2][TPB];
    __shared__ int   m1i[2][TPB];
    __shared__ float m2v[2][TPB];
    __shared__ int   fidx[TPB];
    __shared__ int   flist[TPB];
    __shared__ int   fcount, lastFlag;
    __shared__ double lred[4];

    const int tid  = threadIdx.x;
    const int lane = tid & 63, wave = tid >> 6;
    const int quad = lane >> 4, lrow = lane & 15;
    const int t0   = blockIdx.x * TPB;
    const int wtok = t0 + (wave >> 1) * 64;      // this wave's 64 tokens
    const int c0   = (wave & 1) * 512;           // this wave's code half
    const int half = wave & 1;

    if (tid == 0) fcount = 0;

    // ---- A fragments: straight from global X -> registers (fp16 split, x 2^10) --
    f16x8 a_h0[4], a_h1[4], a_l0[4], a_l1[4];
    #pragma unroll
    for (int rt = 0; rt < 4; ++rt) {
        const float* xrow = X + (size_t)(wtok + rt * 16 + lrow) * DIM;
        f32x4 v0 = *(const f32x4*)(xrow + quad * 8);
        f32x4 v1 = *(const f32x4*)(xrow + quad * 8 + 4);
        f32x4 v2 = *(const f32x4*)(xrow + 32 + quad * 8);
        f32x4 v3 = *(const f32x4*)(xrow + 32 + quad * 8 + 4);
        #pragma unroll
        for (int j = 0; j < 4; ++j) {
            _Float16 h, l;
            split16(v0[j] * XSCALE, h, l); a_h0[rt][j]     = h; a_l0[rt][j]     = l;
            split16(v1[j] * XSCALE, h, l); a_h0[rt][j + 4] = h; a_l0[rt][j + 4] = l;
            split16(v2[j] * XSCALE, h, l); a_h1[rt][j]     = h; a_l1[rt][j]     = l;
            split16(v3[j] * XSCALE, h, l); a_h1[rt][j + 4] = h; a_l1[rt][j + 4] = l;
        }
    }

    float r1v[16], r2v[16]; int r1i[16];
    #pragma unroll
    for (int ri = 0; ri < 16; ++ri) { r1v[ri] = 3.4e38f; r2v[ri] = 3.4e38f; r1i[ri] = 0x7fffffff; }

    // ---- main loop: 32 code-tiles of 16, register double-buffer prefetch --------
    f16x8 bh0[2], bh1[2], bl0[2], bl1[2]; float s2v[2];
    {
        int code = c0 + lrow;
        const _Float16* ph = WhiG + code * 64 + quad * 8;
        const _Float16* pl = WloG + code * 64 + quad * 8;
        bh0[0] = *(const f16x8*)ph; bh1[0] = *(const f16x8*)(ph + 32);
        bl0[0] = *(const f16x8*)pl; bl1[0] = *(const f16x8*)(pl + 32);
        s2v[0] = s2g[code];
    }
    #pragma unroll 2
    for (int tile = 0; tile < 32; ++tile) {
        const int cur = tile & 1;
        if (tile < 31) {                      // prefetch next tile into other slot
            int code = c0 + (tile + 1) * 16 + lrow;
            const _Float16* ph = WhiG + code * 64 + quad * 8;
            const _Float16* pl = WloG + code * 64 + quad * 8;
            bh0[cur ^ 1] = *(const f16x8*)ph; bh1[cur ^ 1] = *(const f16x8*)(ph + 32);
            bl0[cur ^ 1] = *(const f16x8*)pl; bl1[cur ^ 1] = *(const f16x8*)(pl + 32);
            s2v[cur ^ 1] = s2g[code];
        }
        int jcode = c0 + tile * 16 + lrow;    // this lane's C-column code
        float ainit = fmulr(s2v[cur], AINIT_SC);   // -0.5*s2*2^26
        #pragma unroll
        for (int rt = 0; rt < 4; ++rt) {
            f32x4 acc = {ainit, ainit, ainit, ainit};
            acc = __builtin_amdgcn_mfma_f32_16x16x32_f16(a_h0[rt], bh0[cur], acc, 0, 0, 0);
            acc = __builtin_amdgcn_mfma_f32_16x16x32_f16(a_h1[rt], bh1[cur], acc, 0, 0, 0);
            acc = __builtin_amdgcn_mfma_f32_16x16x32_f16(a_h0[rt], bl0[cur], acc, 0, 0, 0);
            acc = __builtin_amdgcn_mfma_f32_16x16x32_f16(a_h1[rt], bl1[cur], acc, 0, 0, 0);
            acc = __builtin_amdgcn_mfma_f32_16x16x32_f16(a_l0[rt], bh0[cur], acc, 0, 0, 0);
            acc = __builtin_amdgcn_mfma_f32_16x16x32_f16(a_l1[rt], bh1[cur], acc, 0, 0, 0);
            #pragma unroll
            for (int r = 0; r < 4; ++r) {
                float d = fmulr(acc[r], D_UNSC);   // -2*acc/2^26
                int ri = rt * 4 + r;
                bool lt = d < r1v[ri];             // strict: earliest code on ties
                float sec = lt ? r1v[ri] : d;
                r2v[ri] = fminf(r2v[ri], sec);
                r1v[ri] = lt ? d : r1v[ri];
                r1i[ri] = lt ? jcode : r1i[ri];
            }
        }
    }

    // ---- butterfly top-2 merge across the 16 lrow lanes (codes disjoint) --------
    #pragma unroll
    for (int m = 1; m <= 8; m <<= 1) {
        #pragma unroll
        for (int ri = 0; ri < 16; ++ri) {
            float o1v = __shfl_xor(r1v[ri], m, 64);
            int   o1i = __shfl_xor(r1i[ri], m, 64);
            float o2v = __shfl_xor(r2v[ri], m, 64);
            bool take = (o1v < r1v[ri]) || (o1v == r1v[ri] && o1i < r1i[ri]);
            float loser = take ? r1v[ri] : o1v;
            r2v[ri] = fminf(fminf(r2v[ri], o2v), loser);
            if (take) { r1v[ri] = o1v; r1i[ri] = o1i; }
        }
    }
    if (lrow == 0) {
        #pragma unroll
        for (int ri = 0; ri < 16; ++ri) {
            int rt = ri >> 2, r = ri & 3;
            int tloc = (wave >> 1) * 64 + rt * 16 + quad * 4 + r;
            m1v[half][tloc] = r1v[ri];
            m1i[half][tloc] = r1i[ri];
            m2v[half][tloc] = r2v[ri];
        }
    }
    __syncthreads();

    // ---- merge code-halves per token; margin test ------------------------------
    if (tid < TPB) {
        float v0 = m1v[0][tid], v1 = m1v[1][tid];
        bool t1 = v1 < v0;                       // strict: half0 (smaller idx) on tie
        float b1v = t1 ? v1 : v0;
        int   b1i = t1 ? m1i[1][tid] : m1i[0][tid];
        float loser = t1 ? v0 : v1;
        float b2v = fminf(fminf(m2v[0][tid], m2v[1][tid]), loser);
        bool fb = (b2v - b1v) < MARGIN;
        fidx[tid] = fb ? (b1i | (int)0x80000000) : b1i;
        if (fb) { int p = atomicAdd(&fcount, 1); flist[p] = tid; }
    }
    __syncthreads();

    // ---- epilogue for certain tokens, float4-vectorized ------------------------
    double lsum = 0.0;
    #pragma unroll
    for (int i = 0; i < 8; ++i) {
        int e4 = tid + NTH * i;                  // 0..2047 float4 groups
        int t = e4 >> 4, d4 = (e4 & 15) * 4;
        int iv = fidx[t];
        if (iv >= 0) {
            f32x4 q = *(const f32x4*)&W[iv * 64 + d4];
            f32x4 x = *(const f32x4*)&X[(size_t)(t0 + t) * 64 + d4];
            *(f32x4*)&out[(size_t)OFF_Q + (size_t)(t0 + t) * 64 + d4] = q;
            #pragma unroll
            for (int c = 0; c < 4; ++c) {
                float df = __fsub_rn(q[c], x[c]);
                lsum += (double)fmulr(df, df);
            }
        }
    }
    #pragma unroll
    for (int off = 32; off >= 1; off >>= 1) lsum += __shfl_down(lsum, off, 64);
    if (lane == 0) lred[wave] = lsum;
    if (tid < TPB) {
        int iv = fidx[tid];
        if (iv >= 0) {
            atomicAdd(&counts[iv], 1);
            out[(size_t)OFF_IDX + t0 + tid] = (float)iv;
        }
    }
    __syncthreads();
    if (tid == 0) atomicAdd(loss_acc, lred[0] + lred[1] + lred[2] + lred[3]);

    // ---- in-block exact fallback: one wave per marginal token, W from L2 --------
    // bit-exact round-1 arithmetic: sequential-k fp32 FMA chain, np tie-break
    for (int fi = wave; fi < fcount; fi += 4) {
        int t = flist[fi];
        int gtok = t0 + t;
        float s1v = sumsq64_np(X + (size_t)gtok * 64);   // broadcast loads
        f32x4 xr[16];
        #pragma unroll
        for (int kb = 0; kb < 16; ++kb)
            xr[kb] = *(const f32x4*)(X + (size_t)gtok * 64 + kb * 4);
        unsigned long long best = ~0ULL;
        #pragma unroll 1
        for (int c16 = 0; c16 < 16; ++c16) {
            int code = lane * 16 + c16;
            const float* wr = W + code * 64;
            float acc = 0.0f;
            #pragma unroll
            for (int kb = 0; kb < 16; ++kb) {
                f32x4 wv = *(const f32x4*)(wr + kb * 4);
                acc = __builtin_fmaf(xr[kb][0], wv[0], acc);
                acc = __builtin_fmaf(xr[kb][1], wv[1], acc);
                acc = __builtin_fmaf(xr[kb][2], wv[2], acc);
                acc = __builtin_fmaf(xr[kb][3], wv[3], acc);
            }
            float d = faddr(faddr(s1v, s2g[code]), fmulr(-2.0f, acc));
            unsigned long long pk = ((unsigned long long)keyf(d) << 32) | (unsigned)code;
            best = pk < best ? pk : best;
        }
        #pragma unroll
        for (int m = 32; m >= 1; m >>= 1) {
            unsigned long long o = __shfl_xor(best, m, 64);
            best = o < best ? o : best;
        }
        int idx = (int)(best & 0xffffffffu);
        float q = W[idx * 64 + lane];
        float x = X[(size_t)gtok * 64 + lane];
        out[(size_t)OFF_Q + (size_t)gtok * 64 + lane] = q;
        float df = __fsub_rn(q, x);
        double ls = (double)fmulr(df, df);
        #pragma unroll
        for (int m = 32; m >= 1; m >>= 1) ls += __shfl_xor(ls, m, 64);
        if (lane == 0) {
            out[(size_t)OFF_IDX + gtok] = (float)idx;
            atomicAdd(&counts[idx], 1);
            atomicAdd(loss_acc, ls);
        }
    }

    // ---- merged finale: last block to finish computes loss & perplexity ---------
    __syncthreads();
    if (tid == 0) {
        __threadfence();
        int old = atomicAdd(ticket, 1);
        lastFlag = (old == NBLK - 1) ? 1 : 0;
    }
    __syncthreads();
    if (lastFlag) {
        double h = 0.0;
        for (int j = tid; j < K_CODES; j += NTH) {
            int c = atomicAdd(&counts[j], 0);        // device-coherent read
            double p = (double)c / 65536.0;
            h += p * log(p + 1e-10);
        }
        #pragma unroll
        for (int off = 32; off >= 1; off >>= 1) h += __shfl_down(h, off, 64);
        if (lane == 0) lred[wave] = h;
        __syncthreads();
        if (tid == 0) {
            double H = lred[0] + lred[1] + lred[2] + lred[3];
            out[OFF_PERP] = (float)exp(-H);
            double ls = atomicAdd(loss_acc, 0.0);    // device-coherent read
            float Lf = (float)(ls / 4194304.0);
            out[0] = faddr(Lf, fmulr(0.25f, Lf));
        }
    }
}

extern "C" void kernel_launch(void* const* d_in, const int* in_sizes, int n_in,
                              void* d_out, int out_size, void* d_ws, size_t ws_size,
                              hipStream_t stream) {
    const float* X = (const float*)d_in[0];
    const float* W = (const float*)d_in[1];
    float* out = (float*)d_out;
    char* ws = (char*)d_ws;
    double* loss_acc = (double*)(ws + WS_LOSS);
    int* ticket = (int*)(ws + WS_TICKET);
    int* counts = (int*)(ws + WS_COUNTS);
    _Float16* Whi = (_Float16*)(ws + WS_WHI);
    _Float16* Wlo = (_Float16*)(ws + WS_WLO);
    float* s2g = (float*)(ws + WS_S2);

    vq_prep<<<128, NTH, 0, stream>>>(W, Whi, Wlo, s2g, counts, ticket, loss_acc);
    vq_main<<<NBLK, NTH, 0, stream>>>(X, W, Whi, Wlo, s2g, out,
                                      loss_acc, counts, ticket);
}